// Round 2
// baseline (1019.257 us; speedup 1.0000x reference)
//
#include <hip/hip_runtime.h>
#include <hip/hip_bf16.h>

// Problem constants (fixed by reference)
#define Bn 16
#define Tn 64
#define Nn 256
#define Kn 8
#define dn 8
#define Dn 64
#define TDn 128   // 2*D

__device__ __forceinline__ float b2f(const __hip_bfloat16 x) { return __bfloat162float(x); }
__device__ __forceinline__ float geluf(float x) {
    // exact erf GELU (torch F.gelu default)
    return 0.5f * x * (1.0f + erff(x * 0.70710678118654752440f));
}

// One block per (b, n). 256 threads = 4 waves.
// LDS: Ht bf16 (padded) + q/k fp32 (stride 65) + v bf16 (stride 66) = 58,624 B -> 2 blocks/CU.
__global__ __launch_bounds__(256, 2)
void tam_fused(const float* __restrict__ X,
               const float* __restrict__ STE,
               const float* __restrict__ W12, const float* __restrict__ b12,
               const float* __restrict__ W13, const float* __restrict__ b13,
               const float* __restrict__ W14, const float* __restrict__ b14,
               const float* __restrict__ W15, const float* __restrict__ b15,
               const float* __restrict__ W16, const float* __restrict__ b16,
               float* __restrict__ Out)
{
    __shared__ __hip_bfloat16 Ht[TDn][66];   // 16,896 B  H^T: [i][t], pad 66 -> conflict-free
    __shared__ float          qs[Tn][65];    // 16,640 B  q (later: attention output)
    __shared__ float          ks[Tn][65];    // 16,640 B  k (later: MLP hidden)
    __shared__ __hip_bfloat16 vs[Tn][66];    //  8,448 B  v (bf16 is enough for PV)

    const int bn   = blockIdx.x;
    const int b    = bn >> 8;     // / Nn
    const int n    = bn & 255;    // % Nn
    const int tid  = threadIdx.x;
    const int lane = tid & 63;
    const int wv   = __builtin_amdgcn_readfirstlane(tid >> 6);  // wave id, force SGPR

    // ---------------- Phase 1: stage H^T = concat(X, STE) into LDS (fp32 -> bf16) ----------
    {
        const size_t base = ((size_t)b * Tn * Nn + n) * Dn;
        for (int idx = tid; idx < Tn * TDn; idx += 256) {
            const int t = idx >> 7;     // row (time)
            const int i = idx & 127;    // feature in [0,128)
            const size_t g = base + (size_t)t * (Nn * Dn);
            const float hv = (i < Dn) ? X[g + i] : STE[g + (i - Dn)];
            Ht[i][t] = __float2bfloat16(hv);
        }
    }
    __syncthreads();

    // ---------------- Phase 2: q,k,v = gelu(H @ W.T + b) ----------------
    // Thread (r = lane) owns row r; wave owns 16 cols of each of q/k/v.
    // Weight addresses are wave-uniform -> scalar loads.
    {
        const int c0 = wv * 16;
        const int r  = lane;
        float aq[16], ak[16], av[16];
        #pragma unroll
        for (int j = 0; j < 16; ++j) {
            aq[j] = b12[c0 + j];
            ak[j] = b13[c0 + j];
            av[j] = b14[c0 + j];
        }
        #pragma unroll 4
        for (int i = 0; i < TDn; ++i) {
            const float h = b2f(Ht[i][r]);   // conflict-free (pairs share a dword -> broadcast)
            #pragma unroll
            for (int j = 0; j < 16; ++j) {
                aq[j] += h * W12[(c0 + j) * TDn + i];
                ak[j] += h * W13[(c0 + j) * TDn + i];
                av[j] += h * W14[(c0 + j) * TDn + i];
            }
        }
        #pragma unroll
        for (int j = 0; j < 16; ++j) {
            qs[r][c0 + j] = geluf(aq[j]);                      // (r + c) % 32 -> 2-way = free
            ks[r][c0 + j] = geluf(ak[j]);
            vs[r][c0 + j] = __float2bfloat16(geluf(av[j]));
        }
    }
    __syncthreads();

    // ---------------- Phase 3: causal attention per (t, head), online softmax ----------------
    // 512 (t,head) tasks; thread (lane=t, wave=wv) does heads wv and wv+4.
    // k/v reads are wave-uniform -> LDS broadcast (free).
    {
        const float scale = 0.35355339059327373f;  // 1/sqrt(8)
        const int t = lane;
        #pragma unroll
        for (int hh = 0; hh < 2; ++hh) {
            const int c = (wv + hh * 4) * dn;      // head column base
            float qv[8];
            #pragma unroll
            for (int dd = 0; dd < 8; ++dd) qv[dd] = qs[t][c + dd];
            float m = -3.0e38f, l = 0.0f;
            float o[8] = {0, 0, 0, 0, 0, 0, 0, 0};
            #pragma unroll 8
            for (int j = 0; j < Tn; ++j) {
                float acc = 0.0f;
                #pragma unroll
                for (int dd = 0; dd < 8; ++dd) acc += qv[dd] * ks[j][c + dd];
                acc *= scale;
                acc = (j <= t) ? acc : -3.0e38f;   // causal mask (ref uses -9e15 -> softmax 0)
                const float mn   = fmaxf(m, acc);
                const float corr = __expf(m - mn);
                const float p    = (j <= t) ? __expf(acc - mn) : 0.0f;
                l = l * corr + p;
                #pragma unroll
                for (int dd = 0; dd < 8; ++dd) o[dd] = o[dd] * corr + p * b2f(vs[j][c + dd]);
                m = mn;
            }
            const float inv = 1.0f / l;
            #pragma unroll
            for (int dd = 0; dd < 8; ++dd) qs[t][c + dd] = o[dd] * inv;  // overwrite own q slot
        }
    }
    __syncthreads();

    // ---------------- Phase 4a: hidden = gelu(attn_out @ W15.T + b15) -> ks ----------------
    {
        const int r  = lane;
        const int c0 = wv * 16;
        float a1[16];
        #pragma unroll
        for (int j = 0; j < 16; ++j) a1[j] = b15[c0 + j];
        #pragma unroll 4
        for (int i = 0; i < Dn; ++i) {
            const float x = qs[r][i];
            #pragma unroll
            for (int j = 0; j < 16; ++j) a1[j] += x * W15[(c0 + j) * Dn + i];
        }
        #pragma unroll
        for (int j = 0; j < 16; ++j) ks[r][c0 + j] = geluf(a1[j]);
    }
    __syncthreads();

    // ---------------- Phase 4b: out = hidden @ W16.T + b16 -> global (fp32) ----------------
    {
        const int r  = lane;
        const int c0 = wv * 16;
        float a2[16];
        #pragma unroll
        for (int j = 0; j < 16; ++j) a2[j] = b16[c0 + j];
        #pragma unroll 4
        for (int i = 0; i < Dn; ++i) {
            const float x = ks[r][i];
            #pragma unroll
            for (int j = 0; j < 16; ++j) a2[j] += x * W16[(c0 + j) * Dn + i];
        }
        const size_t obase = ((size_t)(b * Tn + r) * Nn + n) * Dn + c0;
        float4* dst = reinterpret_cast<float4*>(Out + obase);   // 64B-aligned (c0 % 16 == 0)
        dst[0] = make_float4(a2[0],  a2[1],  a2[2],  a2[3]);
        dst[1] = make_float4(a2[4],  a2[5],  a2[6],  a2[7]);
        dst[2] = make_float4(a2[8],  a2[9],  a2[10], a2[11]);
        dst[3] = make_float4(a2[12], a2[13], a2[14], a2[15]);
    }
}

extern "C" void kernel_launch(void* const* d_in, const int* in_sizes, int n_in,
                              void* d_out, int out_size, void* d_ws, size_t ws_size,
                              hipStream_t stream)
{
    (void)in_sizes; (void)n_in; (void)out_size; (void)d_ws; (void)ws_size;
    const float* X   = (const float*)d_in[0];
    const float* STE = (const float*)d_in[1];
    const float* W12 = (const float*)d_in[2];
    const float* b12 = (const float*)d_in[3];
    const float* W13 = (const float*)d_in[4];
    const float* b13 = (const float*)d_in[5];
    const float* W14 = (const float*)d_in[6];
    const float* b14 = (const float*)d_in[7];
    const float* W15 = (const float*)d_in[8];
    const float* b15 = (const float*)d_in[9];
    const float* W16 = (const float*)d_in[10];
    const float* b16 = (const float*)d_in[11];
    float* Out = (float*)d_out;

    hipLaunchKernelGGL(tam_fused, dim3(Bn * Nn), dim3(256), 0, stream,
                       X, STE, W12, b12, W13, b13, W14, b14, W15, b15, W16, b16, Out);
}

// Round 3
// 440.895 us; speedup vs baseline: 2.3118x; 2.3118x over previous
//
#include <hip/hip_runtime.h>
#include <hip/hip_bf16.h>

// Problem constants (fixed by reference)
#define Bn 16
#define Tn 64
#define Nn 256
#define Kn 8
#define dn 8
#define Dn 64
#define TDn 128   // 2*D

typedef __bf16 bf16x8 __attribute__((ext_vector_type(8)));
typedef __bf16 bf16x2 __attribute__((ext_vector_type(2)));
typedef float  f32x4  __attribute__((ext_vector_type(4)));

__device__ __forceinline__ float geluf(float x) {
    // exact erf GELU (torch F.gelu default)
    return 0.5f * x * (1.0f + erff(x * 0.70710678118654752440f));
}

// ---- Kernel 1: convert all weights fp32 -> bf16 into d_ws (runs every launch; ws re-poisoned) ----
// ws layout (bf16 elements): [0,24576) Wqkv rows: 0-63=W12, 64-127=W13, 128-191=W14 (each row 128 k)
//                            [24576,28672) W15 [64][64]; [28672,32768) W16 [64][64]
__global__ void convert_weights(const float* __restrict__ W12, const float* __restrict__ W13,
                                const float* __restrict__ W14, const float* __restrict__ W15,
                                const float* __restrict__ W16, __bf16* __restrict__ ws)
{
    const int i = blockIdx.x * 256 + threadIdx.x;   // 0..32767
    float v;
    if      (i < 8192)  v = W12[i];
    else if (i < 16384) v = W13[i - 8192];
    else if (i < 24576) v = W14[i - 16384];
    else if (i < 28672) v = W15[i - 24576];
    else                v = W16[i - 28672];
    ws[i] = (__bf16)v;
}

// ---- Kernel 2: fused block per (b,n); 256 threads = 4 waves; MFMA for QKV + MLP ----
// LDS 45,056 B -> 3 blocks/CU (12 waves).
__global__ __launch_bounds__(256, 3)
void tam_fused(const float* __restrict__ X,
               const float* __restrict__ STE,
               const float* __restrict__ b12, const float* __restrict__ b13,
               const float* __restrict__ b14, const float* __restrict__ b15,
               const float* __restrict__ b16,
               const __bf16* __restrict__ Wb,   // converted weights in ws
               float* __restrict__ Out)
{
    __shared__ __bf16 Hs[Tn][136];   // 17,408 B  H row-major [t][i], stride 272B: frag reads 2-way=free
    __shared__ __bf16 qs[Tn][72];    //  9,216 B  q -> attn-out
    __shared__ __bf16 ks[Tn][72];    //  9,216 B  k -> MLP hidden
    __shared__ __bf16 vs[Tn][72];    //  9,216 B  v

    const int bn   = blockIdx.x;
    const int b    = bn >> 8;     // / Nn
    const int n    = bn & 255;    // % Nn
    const int tid  = threadIdx.x;
    const int lane = tid & 63;
    const int wv   = __builtin_amdgcn_readfirstlane(tid >> 6);
    const int cl   = lane & 15;          // MFMA col-in-tile / A-row-in-tile
    const int kb   = (lane >> 4) * 8;    // MFMA k-offset
    const int m0   = wv * 16;            // this wave's row-tile

    const __bf16* Wqkv = Wb;             // [192][128]
    const __bf16* W15b = Wb + 24576;     // [64][64]
    const __bf16* W16b = Wb + 28672;     // [64][64]

    // ---------------- Phase 1: stage H = concat(X, STE) row-major, fp32 -> bf16 ----------------
    {
        const size_t base = ((size_t)b * Tn * Nn + n) * Dn;
        for (int t = wv; t < Tn; t += 4) {
            const size_t rb = base + (size_t)t * (Nn * Dn);
            const float2 v2 = (lane < 32)
                ? reinterpret_cast<const float2*>(X + rb)[lane]
                : reinterpret_cast<const float2*>(STE + rb)[lane - 32];
            bf16x2 p; p[0] = (__bf16)v2.x; p[1] = (__bf16)v2.y;
            *reinterpret_cast<bf16x2*>(&Hs[t][2 * lane]) = p;
        }
    }
    __syncthreads();

    // ---------------- Phase 2: qkv = gelu(H @ Wqkv^T + b) via MFMA ----------------
    {
        bf16x8 af[4];
        #pragma unroll
        for (int kk = 0; kk < 4; ++kk)
            af[kk] = *reinterpret_cast<const bf16x8*>(&Hs[m0 + cl][kk * 32 + kb]);

        #pragma unroll 4
        for (int nt = 0; nt < 12; ++nt) {
            const int n0 = nt * 16;
            f32x4 acc = {0.f, 0.f, 0.f, 0.f};
            #pragma unroll
            for (int kk = 0; kk < 4; ++kk) {
                const bf16x8 bf = *reinterpret_cast<const bf16x8*>(
                    &Wqkv[(n0 + cl) * TDn + kk * 32 + kb]);
                acc = __builtin_amdgcn_mfma_f32_16x16x32_bf16(af[kk], bf, acc, 0, 0, 0);
            }
            const float bias = (n0 < 64) ? b12[n0 + cl]
                             : (n0 < 128) ? b13[n0 - 64 + cl]
                                          : b14[n0 - 128 + cl];
            #pragma unroll
            for (int r = 0; r < 4; ++r) {
                const int row = m0 + (lane >> 4) * 4 + r;   // verified C/D: col=lane&15, row=quad*4+r
                const __bf16 g = (__bf16)geluf(acc[r] + bias);
                if      (n0 < 64)  qs[row][n0 + cl]        = g;
                else if (n0 < 128) ks[row][n0 - 128 + 64 + cl] = g;  // n0-64
                else               vs[row][n0 - 128 + cl]  = g;
            }
        }
    }
    __syncthreads();

    // ---------------- Phase 3: causal attention, online softmax (VALU) ----------------
    // Wave wv owns t in [16wv, 16wv+16): causal loop bound 16wv+16 (1.6x less work than flat).
    // lane -> (t_local = lane&15, head = lane>>4 (+4 on second pass)).
    {
        const float scale = 0.35355339059327373f;  // 1/sqrt(8)
        const int t    = m0 + cl;
        const int jend = m0 + 16;
        #pragma unroll
        for (int hh = 0; hh < 2; ++hh) {
            const int c = ((lane >> 4) + 4 * hh) * dn;   // head column base
            float qv[8];
            {
                const bf16x8 qq = *reinterpret_cast<const bf16x8*>(&qs[t][c]);
                #pragma unroll
                for (int dd = 0; dd < 8; ++dd) qv[dd] = (float)qq[dd];
            }
            float m = -3.0e38f, l = 0.0f;
            float o[8] = {0, 0, 0, 0, 0, 0, 0, 0};
            for (int j = 0; j < jend; ++j) {
                const bf16x8 k8 = *reinterpret_cast<const bf16x8*>(&ks[j][c]);
                float acc = 0.0f;
                #pragma unroll
                for (int dd = 0; dd < 8; ++dd) acc += qv[dd] * (float)k8[dd];
                acc *= scale;
                const bool ok = (j <= t);
                acc = ok ? acc : -3.0e38f;
                const float mn   = fmaxf(m, acc);
                const float corr = __expf(m - mn);
                const float p    = ok ? __expf(acc - mn) : 0.0f;
                l = l * corr + p;
                const bf16x8 v8 = *reinterpret_cast<const bf16x8*>(&vs[j][c]);
                #pragma unroll
                for (int dd = 0; dd < 8; ++dd) o[dd] = o[dd] * corr + p * (float)v8[dd];
                m = mn;
            }
            const float inv = 1.0f / l;
            bf16x8 ov;
            #pragma unroll
            for (int dd = 0; dd < 8; ++dd) ov[dd] = (__bf16)(o[dd] * inv);
            *reinterpret_cast<bf16x8*>(&qs[t][c]) = ov;   // own slot; heads 4-7 untouched by hh=0
        }
    }
    __syncthreads();

    // ---------------- Phase 4a: hidden = gelu(attn_out @ W15^T + b15) -> ks (MFMA) ----------------
    {
        const bf16x8 a0 = *reinterpret_cast<const bf16x8*>(&qs[m0 + cl][kb]);
        const bf16x8 a1 = *reinterpret_cast<const bf16x8*>(&qs[m0 + cl][32 + kb]);
        #pragma unroll
        for (int nt = 0; nt < 4; ++nt) {
            const int n0 = nt * 16;
            f32x4 acc = {0.f, 0.f, 0.f, 0.f};
            const bf16x8 bf0 = *reinterpret_cast<const bf16x8*>(&W15b[(n0 + cl) * Dn + kb]);
            acc = __builtin_amdgcn_mfma_f32_16x16x32_bf16(a0, bf0, acc, 0, 0, 0);
            const bf16x8 bf1 = *reinterpret_cast<const bf16x8*>(&W15b[(n0 + cl) * Dn + 32 + kb]);
            acc = __builtin_amdgcn_mfma_f32_16x16x32_bf16(a1, bf1, acc, 0, 0, 0);
            const float bias = b15[n0 + cl];
            #pragma unroll
            for (int r = 0; r < 4; ++r) {
                const int row = m0 + (lane >> 4) * 4 + r;
                ks[row][n0 + cl] = (__bf16)geluf(acc[r] + bias);
            }
        }
    }
    __syncthreads();

    // ---------------- Phase 4b: out = hidden @ W16^T + b16 -> global fp32 ----------------
    {
        const bf16x8 a0 = *reinterpret_cast<const bf16x8*>(&ks[m0 + cl][kb]);
        const bf16x8 a1 = *reinterpret_cast<const bf16x8*>(&ks[m0 + cl][32 + kb]);
        #pragma unroll
        for (int nt = 0; nt < 4; ++nt) {
            const int n0 = nt * 16;
            f32x4 acc = {0.f, 0.f, 0.f, 0.f};
            const bf16x8 bf0 = *reinterpret_cast<const bf16x8*>(&W16b[(n0 + cl) * Dn + kb]);
            acc = __builtin_amdgcn_mfma_f32_16x16x32_bf16(a0, bf0, acc, 0, 0, 0);
            const bf16x8 bf1 = *reinterpret_cast<const bf16x8*>(&W16b[(n0 + cl) * Dn + 32 + kb]);
            acc = __builtin_amdgcn_mfma_f32_16x16x32_bf16(a1, bf1, acc, 0, 0, 0);
            const float bias = b16[n0 + cl];
            #pragma unroll
            for (int r = 0; r < 4; ++r) {
                const int row = m0 + (lane >> 4) * 4 + r;
                Out[((size_t)(b * Tn + row) * Nn + n) * Dn + n0 + cl] = acc[r] + bias;
            }
        }
    }
}

extern "C" void kernel_launch(void* const* d_in, const int* in_sizes, int n_in,
                              void* d_out, int out_size, void* d_ws, size_t ws_size,
                              hipStream_t stream)
{
    (void)in_sizes; (void)n_in; (void)out_size; (void)ws_size;
    const float* X   = (const float*)d_in[0];
    const float* STE = (const float*)d_in[1];
    const float* W12 = (const float*)d_in[2];
    const float* b12 = (const float*)d_in[3];
    const float* W13 = (const float*)d_in[4];
    const float* b13 = (const float*)d_in[5];
    const float* W14 = (const float*)d_in[6];
    const float* b14 = (const float*)d_in[7];
    const float* W15 = (const float*)d_in[8];
    const float* b15 = (const float*)d_in[9];
    const float* W16 = (const float*)d_in[10];
    const float* b16 = (const float*)d_in[11];
    float* Out = (float*)d_out;
    __bf16* ws = (__bf16*)d_ws;   // needs 65,536 B

    hipLaunchKernelGGL(convert_weights, dim3(128), dim3(256), 0, stream,
                       W12, W13, W14, W15, W16, ws);
    hipLaunchKernelGGL(tam_fused, dim3(Bn * Nn), dim3(256), 0, stream,
                       X, STE, b12, b13, b14, b15, b16, ws, Out);
}

// Round 4
// 381.180 us; speedup vs baseline: 2.6740x; 1.1567x over previous
//
#include <hip/hip_runtime.h>
#include <hip/hip_bf16.h>

// Problem constants (fixed by reference)
#define Bn 16
#define Tn 64
#define Nn 256
#define Kn 8
#define dn 8
#define Dn 64
#define TDn 128   // 2*D

typedef __bf16 bf16x8 __attribute__((ext_vector_type(8)));
typedef __bf16 bf16x2 __attribute__((ext_vector_type(2)));
typedef float  f32x4  __attribute__((ext_vector_type(4)));

__device__ __forceinline__ float geluf(float x) {
    // exact erf GELU (torch F.gelu default)
    return 0.5f * x * (1.0f + erff(x * 0.70710678118654752440f));
}

// ---- Kernel 1: convert all weights fp32 -> bf16 into d_ws (runs every launch; ws re-poisoned) ----
// ws layout (bf16): [0,24576) Wqkv rows 0-63=W12,64-127=W13,128-191=W14 (row=128 k)
//                   [24576,28672) W15 [64][64]; [28672,32768) W16 [64][64]
__global__ void convert_weights(const float* __restrict__ W12, const float* __restrict__ W13,
                                const float* __restrict__ W14, const float* __restrict__ W15,
                                const float* __restrict__ W16, __bf16* __restrict__ ws)
{
    const int i = blockIdx.x * 256 + threadIdx.x;   // 0..32767
    float v;
    if      (i < 8192)  v = W12[i];
    else if (i < 16384) v = W13[i - 8192];
    else if (i < 24576) v = W14[i - 16384];
    else if (i < 28672) v = W15[i - 24576];
    else                v = W16[i - 28672];
    ws[i] = (__bf16)v;
}

// ---- Kernel 2: fused block per (b,n); 256 threads = 4 waves ----
// LDS 35,840 B (vs overlays Hs after A-frag preload) -> 4 blocks/CU (16 waves).
__global__ __launch_bounds__(256, 4)
void tam_fused(const float* __restrict__ X,
               const float* __restrict__ STE,
               const float* __restrict__ b12, const float* __restrict__ b13,
               const float* __restrict__ b14, const float* __restrict__ b15,
               const float* __restrict__ b16,
               const __bf16* __restrict__ Wb,   // converted weights in ws
               float* __restrict__ Out)
{
    // Carved LDS: region0 [0,17408) = Hs (phase 1-2) then vs (phase 2 epilogue onward);
    //             qs at 17408 (9216 B), ks at 26624 (9216 B). Total 35,840 B.
    __shared__ __align__(16) char smem[35840];
    __bf16 (*Hs)[136] = reinterpret_cast<__bf16 (*)[136]>(smem);          // [64][136]
    __bf16 (*vs)[72]  = reinterpret_cast<__bf16 (*)[72]>(smem);           // [64][72] overlay
    __bf16 (*qs)[72]  = reinterpret_cast<__bf16 (*)[72]>(smem + 17408);   // [64][72]
    __bf16 (*ks)[72]  = reinterpret_cast<__bf16 (*)[72]>(smem + 26624);   // [64][72]

    const int bn   = blockIdx.x;
    const int b    = bn >> 8;     // / Nn
    const int n    = bn & 255;    // % Nn
    const int tid  = threadIdx.x;
    const int lane = tid & 63;
    const int wv   = __builtin_amdgcn_readfirstlane(tid >> 6);
    const int cl   = lane & 15;          // MFMA col-in-tile / A-row-in-tile
    const int kb   = (lane >> 4) * 8;    // MFMA k-offset (quad*8)
    const int m0   = wv * 16;            // this wave's row-tile

    const __bf16* Wqkv = Wb;             // [192][128]
    const __bf16* W15b = Wb + 24576;     // [64][64]
    const __bf16* W16b = Wb + 28672;     // [64][64]

    // ---------------- Phase 1: stage H = concat(X, STE) row-major, fp32 -> bf16 ----------------
    {
        const size_t base = ((size_t)b * Tn * Nn + n) * Dn;
        for (int t = wv; t < Tn; t += 4) {
            const size_t rb = base + (size_t)t * (Nn * Dn);
            const float2 v2 = (lane < 32)
                ? reinterpret_cast<const float2*>(X + rb)[lane]
                : reinterpret_cast<const float2*>(STE + rb)[lane - 32];
            bf16x2 p; p[0] = (__bf16)v2.x; p[1] = (__bf16)v2.y;
            *reinterpret_cast<bf16x2*>(&Hs[t][2 * lane]) = p;
        }
    }
    __syncthreads();

    // ---------------- Phase 2: qkv = gelu(H @ Wqkv^T + b) via MFMA ----------------
    {
        bf16x8 af[4];
        #pragma unroll
        for (int kk = 0; kk < 4; ++kk)
            af[kk] = *reinterpret_cast<const bf16x8*>(&Hs[m0 + cl][kk * 32 + kb]);
        __syncthreads();   // all waves hold A-frags in regs -> Hs region reusable as vs

        #pragma unroll 4
        for (int nt = 0; nt < 12; ++nt) {
            const int n0 = nt * 16;
            f32x4 acc = {0.f, 0.f, 0.f, 0.f};
            #pragma unroll
            for (int kk = 0; kk < 4; ++kk) {
                const bf16x8 bf = *reinterpret_cast<const bf16x8*>(
                    &Wqkv[(n0 + cl) * TDn + kk * 32 + kb]);
                acc = __builtin_amdgcn_mfma_f32_16x16x32_bf16(af[kk], bf, acc, 0, 0, 0);
            }
            const float bias = (n0 < 64) ? b12[n0 + cl]
                             : (n0 < 128) ? b13[n0 - 64 + cl]
                                          : b14[n0 - 128 + cl];
            #pragma unroll
            for (int r = 0; r < 4; ++r) {
                const int row = m0 + (lane >> 4) * 4 + r;   // verified C/D: col=lane&15, row=quad*4+r
                const __bf16 g = (__bf16)geluf(acc[r] + bias);
                if      (n0 < 64)  qs[row][n0 + cl]       = g;
                else if (n0 < 128) ks[row][n0 - 64 + cl]  = g;
                else               vs[row][n0 - 128 + cl] = g;
            }
        }
    }
    __syncthreads();

    // ---------------- Phase 3: causal attention, online softmax (VALU), load-balanced ----------
    // Slot 0: (t = m0+cl, head = lane>>4);  Slot 1: (t = 63-(m0+cl), head = lane>>4 + 4).
    // Per-wave loop totals: (m0+16) + (64-m0) = 80 for EVERY wave (was 128 on wave 3).
    // Slot 0 writes head-cols 0-31 only; slot 1 reads q from cols 32-63 -> disjoint, no barrier.
    {
        const float scale = 0.35355339059327373f;  // 1/sqrt(8)
        #pragma unroll
        for (int slot = 0; slot < 2; ++slot) {
            const int t    = slot ? (63 - (m0 + cl)) : (m0 + cl);
            const int c    = ((lane >> 4) + 4 * slot) * dn;   // head column base
            const int jend = slot ? (Tn - m0) : (m0 + 16);    // wave-uniform, multiple of 16
            float qv[8];
            {
                const bf16x8 qq = *reinterpret_cast<const bf16x8*>(&qs[t][c]);
                #pragma unroll
                for (int dd = 0; dd < 8; ++dd) qv[dd] = (float)qq[dd];
            }
            float m = -3.0e38f, l = 0.0f;
            float o[8] = {0, 0, 0, 0, 0, 0, 0, 0};
            for (int j0 = 0; j0 < jend; j0 += 4) {
                #pragma unroll
                for (int jj = 0; jj < 4; ++jj) {
                    const int j = j0 + jj;
                    const bf16x8 k8 = *reinterpret_cast<const bf16x8*>(&ks[j][c]);
                    float acc = 0.0f;
                    #pragma unroll
                    for (int dd = 0; dd < 8; ++dd) acc += qv[dd] * (float)k8[dd];
                    acc *= scale;
                    const bool ok = (j <= t);
                    acc = ok ? acc : -3.0e38f;
                    const float mn   = fmaxf(m, acc);
                    const float corr = __expf(m - mn);
                    const float p    = ok ? __expf(acc - mn) : 0.0f;
                    l = l * corr + p;
                    const bf16x8 v8 = *reinterpret_cast<const bf16x8*>(&vs[j][c]);
                    #pragma unroll
                    for (int dd = 0; dd < 8; ++dd) o[dd] = o[dd] * corr + p * (float)v8[dd];
                    m = mn;
                }
            }
            const float inv = 1.0f / l;
            bf16x8 ov;
            #pragma unroll
            for (int dd = 0; dd < 8; ++dd) ov[dd] = (__bf16)(o[dd] * inv);
            *reinterpret_cast<bf16x8*>(&qs[t][c]) = ov;   // own (t,head) slot
        }
    }
    __syncthreads();

    // ---------------- Phase 4a: hidden = gelu(attn_out @ W15^T + b15) -> ks (MFMA) ----------------
    {
        const bf16x8 a0 = *reinterpret_cast<const bf16x8*>(&qs[m0 + cl][kb]);
        const bf16x8 a1 = *reinterpret_cast<const bf16x8*>(&qs[m0 + cl][32 + kb]);
        __syncthreads();   // protect ks overwrite below vs phase-3 stragglers? (ks read done: all
                           // waves passed prior barrier; this one orders A-frag reads vs writes)
        #pragma unroll
        for (int nt = 0; nt < 4; ++nt) {
            const int n0 = nt * 16;
            f32x4 acc = {0.f, 0.f, 0.f, 0.f};
            const bf16x8 bf0 = *reinterpret_cast<const bf16x8*>(&W15b[(n0 + cl) * Dn + kb]);
            acc = __builtin_amdgcn_mfma_f32_16x16x32_bf16(a0, bf0, acc, 0, 0, 0);
            const bf16x8 bf1 = *reinterpret_cast<const bf16x8*>(&W15b[(n0 + cl) * Dn + 32 + kb]);
            acc = __builtin_amdgcn_mfma_f32_16x16x32_bf16(a1, bf1, acc, 0, 0, 0);
            const float bias = b15[n0 + cl];
            #pragma unroll
            for (int r = 0; r < 4; ++r) {
                const int row = m0 + (lane >> 4) * 4 + r;
                ks[row][n0 + cl] = (__bf16)geluf(acc[r] + bias);
            }
        }
    }
    __syncthreads();

    // ---------------- Phase 4b: out = hidden @ W16^T + b16 -> global fp32 ----------------
    {
        const bf16x8 a0 = *reinterpret_cast<const bf16x8*>(&ks[m0 + cl][kb]);
        const bf16x8 a1 = *reinterpret_cast<const bf16x8*>(&ks[m0 + cl][32 + kb]);
        #pragma unroll
        for (int nt = 0; nt < 4; ++nt) {
            const int n0 = nt * 16;
            f32x4 acc = {0.f, 0.f, 0.f, 0.f};
            const bf16x8 bf0 = *reinterpret_cast<const bf16x8*>(&W16b[(n0 + cl) * Dn + kb]);
            acc = __builtin_amdgcn_mfma_f32_16x16x32_bf16(a0, bf0, acc, 0, 0, 0);
            const bf16x8 bf1 = *reinterpret_cast<const bf16x8*>(&W16b[(n0 + cl) * Dn + 32 + kb]);
            acc = __builtin_amdgcn_mfma_f32_16x16x32_bf16(a1, bf1, acc, 0, 0, 0);
            const float bias = b16[n0 + cl];
            #pragma unroll
            for (int r = 0; r < 4; ++r) {
                const int row = m0 + (lane >> 4) * 4 + r;
                Out[((size_t)(b * Tn + row) * Nn + n) * Dn + n0 + cl] = acc[r] + bias;
            }
        }
    }
}

extern "C" void kernel_launch(void* const* d_in, const int* in_sizes, int n_in,
                              void* d_out, int out_size, void* d_ws, size_t ws_size,
                              hipStream_t stream)
{
    (void)in_sizes; (void)n_in; (void)out_size; (void)ws_size;
    const float* X   = (const float*)d_in[0];
    const float* STE = (const float*)d_in[1];
    const float* W12 = (const float*)d_in[2];
    const float* b12 = (const float*)d_in[3];
    const float* W13 = (const float*)d_in[4];
    const float* b13 = (const float*)d_in[5];
    const float* W14 = (const float*)d_in[6];
    const float* b14 = (const float*)d_in[7];
    const float* W15 = (const float*)d_in[8];
    const float* b15 = (const float*)d_in[9];
    const float* W16 = (const float*)d_in[10];
    const float* b16 = (const float*)d_in[11];
    float* Out = (float*)d_out;
    __bf16* ws = (__bf16*)d_ws;   // needs 65,536 B

    hipLaunchKernelGGL(convert_weights, dim3(128), dim3(256), 0, stream,
                       W12, W13, W14, W15, W16, ws);
    hipLaunchKernelGGL(tam_fused, dim3(Bn * Nn), dim3(256), 0, stream,
                       X, STE, b12, b13, b14, b15, b16, ws, Out);
}